// Round 12
// baseline (625.445 us; speedup 1.0000x reference)
//
#include <hip/hip_runtime.h>

#define S_LEN 2048
#define NHEAD 24
#define CDIM 64
#define DDIM 256

typedef _Float16 f16x8 __attribute__((ext_vector_type(8)));
typedef float f32x4 __attribute__((ext_vector_type(4)));

__device__ __forceinline__ ushort f2h(float f) {
    _Float16 h = (_Float16)f;
    return __builtin_bit_cast(ushort, h);
}

// pack 8 consecutive f32 -> 8 f16 (register ops only)
__device__ __forceinline__ int4 cvt8(const float* __restrict__ p) {
    float4 a = *(const float4*)p;
    float4 b = *(const float4*)(p + 4);
    f16x8 h;
    h[0] = (_Float16)a.x; h[1] = (_Float16)a.y;
    h[2] = (_Float16)a.z; h[3] = (_Float16)a.w;
    h[4] = (_Float16)b.x; h[5] = (_Float16)b.y;
    h[6] = (_Float16)b.z; h[7] = (_Float16)b.w;
    return __builtin_bit_cast(int4, h);
}

// C = A (MxK,f32) @ W^T (NxK,f32) + bias, MFMA f16 16x16x32, 64x64 tile, 4 waves.
// LDS rows padded 32->40 ushorts (conflict-free).
// mode 0: scatter f16 into Kbuf/Qbuf ([h][i][c]); mode 1: scatter f16 into Vt ([h][d][j]).
__global__ __launch_bounds__(256) void gemm_bt_kernel(
    const float* __restrict__ A, const float* __restrict__ W,
    const float* __restrict__ bias, int M, int N, int K,
    int mode, int hbase,
    ushort* __restrict__ Kbuf, ushort* __restrict__ Qbuf, ushort* __restrict__ Vt)
{
    __shared__ ushort Asub[64 * 40];
    __shared__ ushort Wsub[64 * 40];
    const int tid = threadIdx.x;
    const int wave = tid >> 6, lane = tid & 63;
    const int g = lane >> 4, c = lane & 15;
    const int m0 = blockIdx.y * 64, n0 = blockIdx.x * 64;
    const int srow = tid >> 2;          // 0..63
    const int skk = (tid & 3) * 8;      // 0,8,16,24

    f32x4 acc[4] = {f32x4{0,0,0,0}, f32x4{0,0,0,0}, f32x4{0,0,0,0}, f32x4{0,0,0,0}};

    for (int k0 = 0; k0 < K; k0 += 32) {
        __syncthreads();
        *(int4*)&Asub[srow * 40 + skk] = cvt8(&A[(m0 + srow) * K + k0 + skk]);
        *(int4*)&Wsub[srow * 40 + skk] = cvt8(&W[(n0 + srow) * K + k0 + skk]);
        __syncthreads();
        f16x8 af = *(const f16x8*)&Asub[(wave * 16 + c) * 40 + g * 8];
#pragma unroll
        for (int t = 0; t < 4; t++) {
            f16x8 bf = *(const f16x8*)&Wsub[(t * 16 + c) * 40 + g * 8];
            acc[t] = __builtin_amdgcn_mfma_f32_16x16x32_f16(af, bf, acc[t], 0, 0, 0);
        }
    }

#pragma unroll
    for (int t = 0; t < 4; t++) {
        int n = n0 + t * 16 + c;
        float bv = bias[n];
#pragma unroll
        for (int r = 0; r < 4; r++) {
            int m = m0 + wave * 16 + g * 4 + r;
            ushort u = f2h(acc[t][r] + bv);
            if (mode == 0) {
                int h = hbase + (n >> 7);
                int cc = n & 127;
                if (cc < 64) Kbuf[(h * S_LEN + m) * CDIM + cc] = u;
                else         Qbuf[(h * S_LEN + m) * CDIM + cc - 64] = u;
            } else {
                int h = n >> 8;
                int d = n & 255;
                Vt[(h * DDIM + d) * S_LEN + m] = u;
            }
        }
    }
}

// rot projection: K=4, no bias, f32 math. n = h'*128 + cc, h = 16 + h'
__global__ __launch_bounds__(256) void rot_proj_kernel(
    const float* __restrict__ rot, const float* __restrict__ Wrot,
    ushort* __restrict__ Kbuf, ushort* __restrict__ Qbuf)
{
    int idx = blockIdx.x * 256 + threadIdx.x;   // 2048*1024
    int i = idx >> 10, n = idx & 1023;
    float4 r = *(const float4*)&rot[i * 4];
    float4 w = *(const float4*)&Wrot[n * 4];
    float v = r.x * w.x + r.y * w.y + r.z * w.z + r.w * w.w;
    int h = 16 + (n >> 7), cc = n & 127;
    ushort u = f2h(v);
    if (cc < 64) Kbuf[(h * S_LEN + i) * CDIM + cc] = u;
    else         Qbuf[(h * S_LEN + i) * CDIM + cc - 64] = u;
}

__global__ __launch_bounds__(256) void zero_kernel(float* __restrict__ p) {
    p[blockIdx.x * 256 + threadIdx.x] = 0.f;
}

// Flash attention per (head, 64-row i-tile). Block = 4 waves, wave owns 16 i-rows.
// BARRIER-FREE: Q and V MFMA B-fragments are loaded directly from global/L2
// (lane (c,g) reads 16B at row jc*16+c / t*16+c -> 16x64B contiguous segments).
// Only P round-trips through LDS, and Plds is per-wave private -> no __syncthreads
// anywhere; waves run fully independently and latency overlaps across waves.
__global__ __launch_bounds__(256) void flash_kernel(
    const ushort* __restrict__ Kbuf, const ushort* __restrict__ Qbuf,
    const ushort* __restrict__ Vt, float* __restrict__ Oacc)
{
    __shared__ ushort Plds[4][16 * 72];  // per-wave private, stride 72

    const int tid = threadIdx.x;
    const int wave = tid >> 6, lane = tid & 63;
    const int g = lane >> 4, c = lane & 15;
    const int h = blockIdx.y;
    const int i0 = blockIdx.x * 64 + wave * 16;
    const float SC = 0.51006973f;        // log2(e)/sqrt(8)

    const ushort* Krow = &Kbuf[(h * S_LEN + i0 + c) * CDIM + g * 8];
    f16x8 ka0 = *(const f16x8*)Krow;
    f16x8 ka1 = *(const f16x8*)(Krow + 32);

    const ushort* Qbase = &Qbuf[(h * S_LEN + c) * CDIM + g * 8];
    const ushort* Vbase = &Vt[(h * DDIM + c) * S_LEN + g * 8];

    f32x4 acc[16];
#pragma unroll
    for (int t = 0; t < 16; t++) acc[t] = f32x4{0, 0, 0, 0};
    float mrow[4] = {-1e30f, -1e30f, -1e30f, -1e30f};
    float lrow[4] = {0.f, 0.f, 0.f, 0.f};

    for (int j0 = 0; j0 < S_LEN; j0 += 64) {
        // scores: S[i'][j'] for 16 rows x 64 cols, 4 j-chunks; Q direct from L2
        f32x4 Sf[4];
#pragma unroll
        for (int jc = 0; jc < 4; jc++) {
            const ushort* Qr = Qbase + (j0 + jc * 16) * CDIM;
            f16x8 qb0 = *(const f16x8*)Qr;
            f16x8 qb1 = *(const f16x8*)(Qr + 32);
            f32x4 s = {0, 0, 0, 0};
            s = __builtin_amdgcn_mfma_f32_16x16x32_f16(ka0, qb0, s, 0, 0, 0);
            s = __builtin_amdgcn_mfma_f32_16x16x32_f16(ka1, qb1, s, 0, 0, 0);
#pragma unroll
            for (int r = 0; r < 4; r++) Sf[jc][r] = s[r] * SC;   // exp2 domain
        }

        // online softmax: row stats live in lanes sharing g (16-lane groups)
        float nm[4], alpha[4], rs[4];
#pragma unroll
        for (int r = 0; r < 4; r++)
            nm[r] = fmaxf(fmaxf(Sf[0][r], Sf[1][r]), fmaxf(Sf[2][r], Sf[3][r]));
#pragma unroll
        for (int off = 1; off < 16; off <<= 1)
#pragma unroll
            for (int r = 0; r < 4; r++) nm[r] = fmaxf(nm[r], __shfl_xor(nm[r], off));
#pragma unroll
        for (int r = 0; r < 4; r++) {
            nm[r] = fmaxf(nm[r], mrow[r]);
            alpha[r] = exp2f(mrow[r] - nm[r]);
            rs[r] = 0.f;
        }
#pragma unroll
        for (int jc = 0; jc < 4; jc++)
#pragma unroll
            for (int r = 0; r < 4; r++) {
                float p = exp2f(Sf[jc][r] - nm[r]);
                rs[r] += p;
                Plds[wave][(g * 4 + r) * 72 + jc * 16 + c] = f2h(p);
            }
#pragma unroll
        for (int off = 1; off < 16; off <<= 1)
#pragma unroll
            for (int r = 0; r < 4; r++) rs[r] += __shfl_xor(rs[r], off);
#pragma unroll
        for (int r = 0; r < 4; r++) {
            lrow[r] = lrow[r] * alpha[r] + rs[r];
            mrow[r] = nm[r];
        }
#pragma unroll
        for (int t = 0; t < 16; t++)
#pragma unroll
            for (int r = 0; r < 4; r++) acc[t][r] *= alpha[r];

        // PV: P (16x64) @ V (64x256); P from per-wave LDS (lgkmcnt only),
        // V direct from L2.
        f16x8 pa0 = *(const f16x8*)&Plds[wave][c * 72 + g * 8];
        f16x8 pa1 = *(const f16x8*)&Plds[wave][c * 72 + 32 + g * 8];
#pragma unroll
        for (int t = 0; t < 16; t++) {
            const ushort* Vr = Vbase + (t * 16) * S_LEN + j0;
            f16x8 vb0 = *(const f16x8*)Vr;
            f16x8 vb1 = *(const f16x8*)(Vr + 32);
            acc[t] = __builtin_amdgcn_mfma_f32_16x16x32_f16(pa0, vb0, acc[t], 0, 0, 0);
            acc[t] = __builtin_amdgcn_mfma_f32_16x16x32_f16(pa1, vb1, acc[t], 0, 0, 0);
        }
    }

    // accumulate head partial into shared f32 output (24 heads -> same address)
#pragma unroll
    for (int t = 0; t < 16; t++)
#pragma unroll
        for (int r = 0; r < 4; r++) {
            int i = i0 + g * 4 + r;
            int d = t * 16 + c;
            atomicAdd(&Oacc[i * DDIM + d], acc[t][r] / lrow[r]);
        }
}

__global__ __launch_bounds__(256) void convert_kernel(
    const float* __restrict__ Oacc, float* __restrict__ out)
{
    int idx = blockIdx.x * 256 + threadIdx.x;   // 2048*256
    out[idx] = Oacc[idx];
}

extern "C" void kernel_launch(void* const* d_in, const int* in_sizes, int n_in,
                              void* d_out, int out_size, void* d_ws, size_t ws_size,
                              hipStream_t stream) {
    // Inputs: f32, resolved by element count (safety net), dict-order fallback.
    const float *nodes = 0, *aux = 0, *rot = 0, *W_nodes = 0, *b_nodes = 0,
                *W_aux = 0, *b_aux = 0, *W_rot = 0, *W_val = 0, *b_val = 0;
    int i1024[2] = {-1, -1};
    int n1024 = 0;
    for (int i = 0; i < n_in; ++i) {
        const float* p = (const float*)d_in[i];
        switch (in_sizes[i]) {
            case 524288:  nodes   = p; break;
            case 131072:  aux     = p; break;
            case 8192:    rot     = p; break;
            case 262144:  W_nodes = p; break;
            case 65536:   W_aux   = p; break;
            case 4096:    W_rot   = p; break;
            case 1572864: W_val   = p; break;
            case 6144:    b_val   = p; break;
            case 1024:    if (n1024 < 2) i1024[n1024] = i; n1024++; break;
            default: break;
        }
    }
    if (n1024 == 2) {
        b_nodes = (const float*)d_in[i1024[0]];
        b_aux   = (const float*)d_in[i1024[1]];
    }
    if (!nodes || !aux || !rot || !W_nodes || !b_nodes || !W_aux || !b_aux ||
        !W_rot || !W_val || !b_val) {
        nodes   = (const float*)d_in[0];
        aux     = (const float*)d_in[1];
        rot     = (const float*)d_in[2];
        W_nodes = (const float*)d_in[3];
        b_nodes = (const float*)d_in[4];
        W_aux   = (const float*)d_in[5];
        b_aux   = (const float*)d_in[6];
        W_rot   = (const float*)d_in[7];
        W_val   = (const float*)d_in[8];
        b_val   = (const float*)d_in[9];
    }
    float* out = (float*)d_out;   // reference output dtype is float32

    // ws layout: Oacc f32 (2MB) | K f16 (6.29MB) | Q f16 (6.29MB) | Vt f16 (25.2MB)
    float*  Oacc = (float*)d_ws;
    ushort* Kbuf = (ushort*)(Oacc + S_LEN * DDIM);
    ushort* Qbuf = Kbuf + NHEAD * S_LEN * CDIM;
    ushort* Vt   = Qbuf + NHEAD * S_LEN * CDIM;

    dim3 blk(256);
    zero_kernel<<<dim3(S_LEN * DDIM / 256), blk, 0, stream>>>(Oacc);
    // nodes -> k/q heads 0..7:  M=2048 N=1024 K=256
    gemm_bt_kernel<<<dim3(16, 32), blk, 0, stream>>>(nodes, W_nodes, b_nodes,
        2048, 1024, 256, 0, 0, Kbuf, Qbuf, nullptr);
    // aux -> k/q heads 8..15:  M=2048 N=1024 K=64
    gemm_bt_kernel<<<dim3(16, 32), blk, 0, stream>>>(aux, W_aux, b_aux,
        2048, 1024, 64, 0, 8, Kbuf, Qbuf, nullptr);
    // rot -> k/q heads 16..23 (K=4, no bias)
    rot_proj_kernel<<<dim3(8192), blk, 0, stream>>>(rot, W_rot, Kbuf, Qbuf);
    // nodes -> values, transposed write: M=2048 N=6144 K=256
    gemm_bt_kernel<<<dim3(96, 32), blk, 0, stream>>>(nodes, W_val, b_val,
        2048, 6144, 256, 1, 0, nullptr, nullptr, Vt);
    // attention: 24 heads x 32 i-tiles, accumulate into Oacc
    flash_kernel<<<dim3(32, NHEAD), blk, 0, stream>>>(Kbuf, Qbuf, Vt, Oacc);
    // f32 copy to out
    convert_kernel<<<dim3(2048), blk, 0, stream>>>(Oacc, out);
}

// Round 13
// 298.354 us; speedup vs baseline: 2.0963x; 2.0963x over previous
//
#include <hip/hip_runtime.h>

#define S_LEN 2048
#define NHEAD 24
#define CDIM 64
#define DDIM 256

typedef _Float16 f16x8 __attribute__((ext_vector_type(8)));
typedef float f32x4 __attribute__((ext_vector_type(4)));

__device__ __forceinline__ ushort f2h(float f) {
    _Float16 h = (_Float16)f;
    return __builtin_bit_cast(ushort, h);
}

// pack 8 consecutive f32 -> 8 f16 (register ops only)
__device__ __forceinline__ int4 cvt8(const float* __restrict__ p) {
    float4 a = *(const float4*)p;
    float4 b = *(const float4*)(p + 4);
    f16x8 h;
    h[0] = (_Float16)a.x; h[1] = (_Float16)a.y;
    h[2] = (_Float16)a.z; h[3] = (_Float16)a.w;
    h[4] = (_Float16)b.x; h[5] = (_Float16)b.y;
    h[6] = (_Float16)b.z; h[7] = (_Float16)b.w;
    return __builtin_bit_cast(int4, h);
}

// C = A (MxK,f32) @ W^T (NxK,f32) + bias, MFMA f16 16x16x32, 64x64 tile, 4 waves.
__global__ __launch_bounds__(256) void gemm_bt_kernel(
    const float* __restrict__ A, const float* __restrict__ W,
    const float* __restrict__ bias, int M, int N, int K,
    int mode, int hbase,
    ushort* __restrict__ Kbuf, ushort* __restrict__ Qbuf, ushort* __restrict__ Vt)
{
    __shared__ ushort Asub[64 * 40];
    __shared__ ushort Wsub[64 * 40];
    const int tid = threadIdx.x;
    const int wave = tid >> 6, lane = tid & 63;
    const int g = lane >> 4, c = lane & 15;
    const int m0 = blockIdx.y * 64, n0 = blockIdx.x * 64;
    const int srow = tid >> 2;
    const int skk = (tid & 3) * 8;

    f32x4 acc[4] = {f32x4{0,0,0,0}, f32x4{0,0,0,0}, f32x4{0,0,0,0}, f32x4{0,0,0,0}};

    for (int k0 = 0; k0 < K; k0 += 32) {
        __syncthreads();
        *(int4*)&Asub[srow * 40 + skk] = cvt8(&A[(m0 + srow) * K + k0 + skk]);
        *(int4*)&Wsub[srow * 40 + skk] = cvt8(&W[(n0 + srow) * K + k0 + skk]);
        __syncthreads();
        f16x8 af = *(const f16x8*)&Asub[(wave * 16 + c) * 40 + g * 8];
#pragma unroll
        for (int t = 0; t < 4; t++) {
            f16x8 bf = *(const f16x8*)&Wsub[(t * 16 + c) * 40 + g * 8];
            acc[t] = __builtin_amdgcn_mfma_f32_16x16x32_f16(af, bf, acc[t], 0, 0, 0);
        }
    }

#pragma unroll
    for (int t = 0; t < 4; t++) {
        int n = n0 + t * 16 + c;
        float bv = bias[n];
#pragma unroll
        for (int r = 0; r < 4; r++) {
            int m = m0 + wave * 16 + g * 4 + r;
            ushort u = f2h(acc[t][r] + bv);
            if (mode == 0) {
                int h = hbase + (n >> 7);
                int cc = n & 127;
                if (cc < 64) Kbuf[(h * S_LEN + m) * CDIM + cc] = u;
                else         Qbuf[(h * S_LEN + m) * CDIM + cc - 64] = u;
            } else {
                int h = n >> 8;
                int d = n & 255;
                Vt[(h * DDIM + d) * S_LEN + m] = u;
            }
        }
    }
}

// rot projection: K=4, no bias, f32 math.
__global__ __launch_bounds__(256) void rot_proj_kernel(
    const float* __restrict__ rot, const float* __restrict__ Wrot,
    ushort* __restrict__ Kbuf, ushort* __restrict__ Qbuf)
{
    int idx = blockIdx.x * 256 + threadIdx.x;
    int i = idx >> 10, n = idx & 1023;
    float4 r = *(const float4*)&rot[i * 4];
    float4 w = *(const float4*)&Wrot[n * 4];
    float v = r.x * w.x + r.y * w.y + r.z * w.z + r.w * w.w;
    int h = 16 + (n >> 7), cc = n & 127;
    ushort u = f2h(v);
    if (cc < 64) Kbuf[(h * S_LEN + i) * CDIM + cc] = u;
    else         Qbuf[(h * S_LEN + i) * CDIM + cc - 64] = u;
}

__global__ __launch_bounds__(256) void zero_kernel(float* __restrict__ p) {
    p[blockIdx.x * 256 + threadIdx.x] = 0.f;
}

// Flash attention per (head, 64-row i-tile). 4 waves.
// d-split PV: wave w owns d-slice [w*64, w*64+64) for ALL 64 block rows.
//  - QK: wave w computes scores for its 16 rows (iw..iw+15), full 64-j tile.
//  - P (64x64) + per-row alpha go to SHARED double-buffered LDS.
//  - V fragments: 8 global->register loads per wave per iter (issued at iter
//    top, latency hidden under QK+softmax), reused across 4 i-groups.
//  - Q tile: LDS double-buffered, prefetched one iter ahead.
//  - ONE __syncthreads per iter (barrier n separates all parity-n reads from
//    iter-n+1 overwrites; buffers alternate).
__global__ __launch_bounds__(256) void flash_kernel(
    const ushort* __restrict__ Kbuf, const ushort* __restrict__ Qbuf,
    const ushort* __restrict__ Vt, float* __restrict__ Oacc)
{
    __shared__ ushort Qlds[2][64 * 72];   // [buf][j'][c], stride 72
    __shared__ ushort Plds[2][64 * 72];   // [buf][i'][j'], stride 72
    __shared__ float  Alds[2][64];        // [buf][i'] alpha (reused for 1/l at end)

    const int tid = threadIdx.x;
    const int wave = tid >> 6, lane = tid & 63;
    const int g = lane >> 4, c = lane & 15;
    const int h = blockIdx.y;
    const int i0 = blockIdx.x * 64;       // block rows
    const int iw = i0 + wave * 16;        // this wave's QK rows
    const float SC = 0.51006973f;         // log2(e)/sqrt(8)

    // K a-frags for wave's 16 rows
    const ushort* Krow = &Kbuf[(h * S_LEN + iw + c) * CDIM + g * 8];
    f16x8 ka0 = *(const f16x8*)Krow;
    f16x8 ka1 = *(const f16x8*)(Krow + 32);

    // V base for this wave's d-slice: rows wave*64 + t*16 + c
    const ushort* Vbase = &Vt[(h * DDIM + wave * 64 + c) * S_LEN + g * 8];

    // Q staging indices: thread stages 2 int4s (row = idx>>3, chunk = idx&7)
    const int qi0 = tid, qi1 = tid + 256;
    const int qr0 = qi0 >> 3, qc0 = (qi0 & 7) * 8;
    const int qr1 = qi1 >> 3, qc1 = (qi1 & 7) * 8;

    // pre-stage tile 0 into Qlds[0]
    *(int4*)&Qlds[0][qr0 * 72 + qc0] =
        *(const int4*)&Qbuf[(h * S_LEN + 0 + qr0) * CDIM + qc0];
    *(int4*)&Qlds[0][qr1 * 72 + qc1] =
        *(const int4*)&Qbuf[(h * S_LEN + 0 + qr1) * CDIM + qc1];
    __syncthreads();

    f32x4 acc[16];   // [b*4+t]: rows b*16+g*4+r, cols wave*64+t*16+c
#pragma unroll
    for (int t = 0; t < 16; t++) acc[t] = f32x4{0, 0, 0, 0};
    float mrow[4] = {-1e30f, -1e30f, -1e30f, -1e30f};
    float lrow[4] = {0.f, 0.f, 0.f, 0.f};

    for (int j0 = 0; j0 < S_LEN; j0 += 64) {
        const int cur = (j0 >> 6) & 1, nxt = cur ^ 1;

        // prefetch next Q tile into regs (reads past Qbuf end land in Vt -> safe)
        const int jn = j0 + 64;
        int4 qn0 = *(const int4*)&Qbuf[(h * S_LEN + jn + qr0) * CDIM + qc0];
        int4 qn1 = *(const int4*)&Qbuf[(h * S_LEN + jn + qr1) * CDIM + qc1];

        // V fragments for THIS iter (latency hidden under QK+softmax)
        f16x8 vf0[4], vf1[4];
#pragma unroll
        for (int t = 0; t < 4; t++) {
            const ushort* Vr = Vbase + (t * 16) * S_LEN + j0;
            vf0[t] = *(const f16x8*)Vr;
            vf1[t] = *(const f16x8*)(Vr + 32);
        }

        // QK: scores S[i'][j'] for wave's 16 rows x 64 cols
        f32x4 Sf[4];
#pragma unroll
        for (int jc = 0; jc < 4; jc++) {
            const ushort* Qr = &Qlds[cur][(jc * 16 + c) * 72 + g * 8];
            f16x8 qb0 = *(const f16x8*)Qr;
            f16x8 qb1 = *(const f16x8*)(Qr + 32);
            f32x4 s = {0, 0, 0, 0};
            s = __builtin_amdgcn_mfma_f32_16x16x32_f16(ka0, qb0, s, 0, 0, 0);
            s = __builtin_amdgcn_mfma_f32_16x16x32_f16(ka1, qb1, s, 0, 0, 0);
#pragma unroll
            for (int r = 0; r < 4; r++) Sf[jc][r] = s[r] * SC;   // exp2 domain
        }

        // online softmax over wave's rows
        float nm[4], alpha[4], rs[4];
#pragma unroll
        for (int r = 0; r < 4; r++)
            nm[r] = fmaxf(fmaxf(Sf[0][r], Sf[1][r]), fmaxf(Sf[2][r], Sf[3][r]));
#pragma unroll
        for (int off = 1; off < 16; off <<= 1)
#pragma unroll
            for (int r = 0; r < 4; r++) nm[r] = fmaxf(nm[r], __shfl_xor(nm[r], off));
#pragma unroll
        for (int r = 0; r < 4; r++) {
            nm[r] = fmaxf(nm[r], mrow[r]);
            alpha[r] = exp2f(mrow[r] - nm[r]);
            rs[r] = 0.f;
        }
#pragma unroll
        for (int jc = 0; jc < 4; jc++)
#pragma unroll
            for (int r = 0; r < 4; r++) {
                float p = exp2f(Sf[jc][r] - nm[r]);
                rs[r] += p;
                Plds[cur][(wave * 16 + g * 4 + r) * 72 + jc * 16 + c] = f2h(p);
            }
#pragma unroll
        for (int off = 1; off < 16; off <<= 1)
#pragma unroll
            for (int r = 0; r < 4; r++) rs[r] += __shfl_xor(rs[r], off);
#pragma unroll
        for (int r = 0; r < 4; r++) {
            lrow[r] = lrow[r] * alpha[r] + rs[r];
            mrow[r] = nm[r];
        }
        // publish alpha for the wave's rows (one lane per row)
        if (c == 0) {
#pragma unroll
            for (int r = 0; r < 4; r++)
                Alds[cur][wave * 16 + g * 4 + r] = alpha[r];
        }

        // stage next Q tile
        *(int4*)&Qlds[nxt][qr0 * 72 + qc0] = qn0;
        *(int4*)&Qlds[nxt][qr1 * 72 + qc1] = qn1;

        __syncthreads();   // P + alpha visible; Q[nxt] staged; V frags drained

        // rescale acc by per-row alpha (broadcast reads)
#pragma unroll
        for (int b = 0; b < 4; b++) {
            f32x4 ab = *(const f32x4*)&Alds[cur][b * 16 + g * 4];
#pragma unroll
            for (int t = 0; t < 4; t++)
#pragma unroll
                for (int r = 0; r < 4; r++) acc[b * 4 + t][r] *= ab[r];
        }

        // PV: P(64x64) @ V(64x64-slice); V frags reused across 4 i-groups
#pragma unroll
        for (int b = 0; b < 4; b++) {
            const ushort* Pr = &Plds[cur][(b * 16 + c) * 72 + g * 8];
            f16x8 pa0 = *(const f16x8*)Pr;
            f16x8 pa1 = *(const f16x8*)(Pr + 32);
#pragma unroll
            for (int t = 0; t < 4; t++) {
                acc[b * 4 + t] = __builtin_amdgcn_mfma_f32_16x16x32_f16(pa0, vf0[t], acc[b * 4 + t], 0, 0, 0);
                acc[b * 4 + t] = __builtin_amdgcn_mfma_f32_16x16x32_f16(pa1, vf1[t], acc[b * 4 + t], 0, 0, 0);
            }
        }
    }

    // publish 1/lrow, then scale+accumulate
    __syncthreads();
    if (c == 0) {
#pragma unroll
        for (int r = 0; r < 4; r++)
            Alds[0][wave * 16 + g * 4 + r] = 1.0f / lrow[r];
    }
    __syncthreads();
#pragma unroll
    for (int b = 0; b < 4; b++) {
        f32x4 lb = *(const f32x4*)&Alds[0][b * 16 + g * 4];
#pragma unroll
        for (int t = 0; t < 4; t++)
#pragma unroll
            for (int r = 0; r < 4; r++) {
                int i = i0 + b * 16 + g * 4 + r;
                int d = wave * 64 + t * 16 + c;
                atomicAdd(&Oacc[i * DDIM + d], acc[b * 4 + t][r] * lb[r]);
            }
    }
}

__global__ __launch_bounds__(256) void convert_kernel(
    const float* __restrict__ Oacc, float* __restrict__ out)
{
    int idx = blockIdx.x * 256 + threadIdx.x;
    out[idx] = Oacc[idx];
}

extern "C" void kernel_launch(void* const* d_in, const int* in_sizes, int n_in,
                              void* d_out, int out_size, void* d_ws, size_t ws_size,
                              hipStream_t stream) {
    const float *nodes = 0, *aux = 0, *rot = 0, *W_nodes = 0, *b_nodes = 0,
                *W_aux = 0, *b_aux = 0, *W_rot = 0, *W_val = 0, *b_val = 0;
    int i1024[2] = {-1, -1};
    int n1024 = 0;
    for (int i = 0; i < n_in; ++i) {
        const float* p = (const float*)d_in[i];
        switch (in_sizes[i]) {
            case 524288:  nodes   = p; break;
            case 131072:  aux     = p; break;
            case 8192:    rot     = p; break;
            case 262144:  W_nodes = p; break;
            case 65536:   W_aux   = p; break;
            case 4096:    W_rot   = p; break;
            case 1572864: W_val   = p; break;
            case 6144:    b_val   = p; break;
            case 1024:    if (n1024 < 2) i1024[n1024] = i; n1024++; break;
            default: break;
        }
    }
    if (n1024 == 2) {
        b_nodes = (const float*)d_in[i1024[0]];
        b_aux   = (const float*)d_in[i1024[1]];
    }
    if (!nodes || !aux || !rot || !W_nodes || !b_nodes || !W_aux || !b_aux ||
        !W_rot || !W_val || !b_val) {
        nodes   = (const float*)d_in[0];
        aux     = (const float*)d_in[1];
        rot     = (const float*)d_in[2];
        W_nodes = (const float*)d_in[3];
        b_nodes = (const float*)d_in[4];
        W_aux   = (const float*)d_in[5];
        b_aux   = (const float*)d_in[6];
        W_rot   = (const float*)d_in[7];
        W_val   = (const float*)d_in[8];
        b_val   = (const float*)d_in[9];
    }
    float* out = (float*)d_out;

    // ws layout: Oacc f32 (2MB) | K f16 (6.29MB) | Q f16 (6.29MB) | Vt f16 (25.2MB)
    float*  Oacc = (float*)d_ws;
    ushort* Kbuf = (ushort*)(Oacc + S_LEN * DDIM);
    ushort* Qbuf = Kbuf + NHEAD * S_LEN * CDIM;
    ushort* Vt   = Qbuf + NHEAD * S_LEN * CDIM;

    dim3 blk(256);
    zero_kernel<<<dim3(S_LEN * DDIM / 256), blk, 0, stream>>>(Oacc);
    gemm_bt_kernel<<<dim3(16, 32), blk, 0, stream>>>(nodes, W_nodes, b_nodes,
        2048, 1024, 256, 0, 0, Kbuf, Qbuf, nullptr);
    gemm_bt_kernel<<<dim3(16, 32), blk, 0, stream>>>(aux, W_aux, b_aux,
        2048, 1024, 64, 0, 8, Kbuf, Qbuf, nullptr);
    rot_proj_kernel<<<dim3(8192), blk, 0, stream>>>(rot, W_rot, Kbuf, Qbuf);
    gemm_bt_kernel<<<dim3(96, 32), blk, 0, stream>>>(nodes, W_val, b_val,
        2048, 6144, 256, 1, 0, nullptr, nullptr, Vt);
    flash_kernel<<<dim3(32, NHEAD), blk, 0, stream>>>(Kbuf, Qbuf, Vt, Oacc);
    convert_kernel<<<dim3(2048), blk, 0, stream>>>(Oacc, out);
}